// Round 10
// baseline (103.707 us; speedup 1.0000x reference)
//
#include <hip/hip_runtime.h>
#include <hip/hip_bf16.h>
#include <math.h>

// Batch-hard triplet loss, B=8192, D=128, fp32 in.
// dist^2[i,j] = rowterm[i] + colterm[j] - 2*dot(e1[i], e2[j])
// sqrt & max/min commute -> track max/min of (colterm - 2*dot); dot on bf16
// matrix cores. Target folded into cpos/cneg (finite +-1e30 sentinels).
//
// R17 vs R12-R16: kill INTRA-LOOP SYNC entirely. Five rounds (drain
// removal, counted vmcnt, occupancy, conflict-free LDS) all neutral; tile
// stuck ~33us with rest=58 (43 harness fill + 15 prep/reduce/gaps). The
// shared mechanism never removed: 2 s_barriers/panel quantize 4 waves to
// the slowest wave 32x. R17: each wave stages the 8 fragment-chunks (8 KB)
// it ALONE consumes into a PRIVATE double-buffered LDS region and paces
// itself with its own vmcnt(8) -> ZERO barriers in the main loop. Waves
// 0/2 and 1/3 duplicate staging (2x L2 = 268MB total ~ 8us aggregate,
// below MFMA floor). LDS 72 KB -> 2 blocks/CU (R15: 3-vs-2 not the lever).
// Ledger: B strictly wave-private (own vmcnt suffices - no R13 cross-wave
// trap); cp/cn cross-wave -> prologue issues cp,cn FIRST, stage0 after,
// vmcnt(8) retires exactly cp+cn (oldest 2 of 10), then one __syncthreads.
// Explicit barrier before the post-loop overlay writes. Fragments element-
// identical to R16's verified gather -> absmax 0.

#define DDIM   128
#define SPLITS 8
#define MARGIN 0.2f
#define EPS    1e-6f
#define SENT   1e30f

#define HALF_BYTES   8192          // 8 chunks x 1024 B (32 cols x 128 K bf16)
#define WAVE_LDS     (2 * HALF_BYTES)               // 16 KB/wave, 2 buffers
#define CPCN_BYTES   (2048 * 4)    // 1024 cp + 1024 cn floats

typedef unsigned short ushort_t;
typedef __attribute__((ext_vector_type(8))) short short8;
typedef __attribute__((ext_vector_type(4))) float f32x4;
typedef __attribute__((ext_vector_type(4))) unsigned short ushort4_t;

__device__ __forceinline__ ushort_t f2bf(float f) {   // fp32 -> bf16 RNE
    unsigned int u = __float_as_uint(f);
    u = (u + 0x7FFFu + ((u >> 16) & 1u)) >> 16;
    return (ushort_t)u;
}

__device__ __forceinline__ void g2lds16(const void* g, void* lds) {
    // per-lane global src; wave-uniform lds base, lane i's 16 B at lds+i*16
    __builtin_amdgcn_global_load_lds(
        (const __attribute__((address_space(1))) unsigned int*)g,
        (__attribute__((address_space(3))) unsigned int*)lds,
        16, 0, 0);
}

// ---- kernel 1: bf16 convert + exact fp32 row stats + zero control vars ----
// 8 lanes per row; fully coalesced float4/ushort4. e1b stores bf16(-2*x)
// (exact scale: exp+1 & sign) so MFMA directly yields -2*dot.
__global__ void prep_kernel(const float* __restrict__ e1, const float* __restrict__ e2,
                            const int* __restrict__ target,
                            ushort_t* __restrict__ e1b, ushort_t* __restrict__ e2b,
                            float* __restrict__ rowterm,
                            float* __restrict__ cpos, float* __restrict__ cneg,
                            float* __restrict__ redsum, int* __restrict__ ticket, int B) {
    if (blockIdx.x == 0) {
        if (threadIdx.x == 0) { redsum[0] = 0.f; redsum[1] = 0.f; }
        else if (threadIdx.x == 1) *ticket = 0;
    }
    int gr  = blockIdx.x * 32 + (threadIdx.x >> 3);     // 0..2B-1
    int seg = threadIdx.x & 7;
    bool first = gr < B;
    int r = first ? gr : gr - B;
    const float* src = (first ? e1 : e2) + (size_t)r * DDIM;
    ushort_t*    dst = (first ? e1b : e2b) + (size_t)r * DDIM;
    const float sc = first ? -2.f : 1.f;
    float s = 0.f, n = 0.f;
    #pragma unroll
    for (int it = 0; it < 4; ++it) {
        int e0 = (seg + it * 8) * 4;
        float4 v = *(const float4*)(src + e0);
        ushort4_t o;
        o.x = f2bf(sc * v.x); o.y = f2bf(sc * v.y);
        o.z = f2bf(sc * v.z); o.w = f2bf(sc * v.w);
        *(ushort4_t*)(dst + e0) = o;
        s += v.x + v.y + v.z + v.w;
        n += v.x * v.x + v.y * v.y + v.z * v.z + v.w * v.w;
    }
    #pragma unroll
    for (int m = 1; m <= 4; m <<= 1) {                  // 8-lane group reduce
        s += __shfl_xor(s, m, 64);
        n += __shfl_xor(n, m, 64);
    }
    if (seg == 0) {
        if (first) {
            rowterm[r] = n + 2.f * EPS * s + (float)DDIM * EPS * EPS;
        } else {
            float ct = n - 2.f * EPS * s;
            int tg = target[r];
            cpos[r] = (tg == 1) ? ct : -SENT;
            cneg[r] = (tg == 0) ? ct :  SENT;
        }
    }
}

// stage THIS WAVE's half of a 64-col panel in fragment order: 8 chunks
// (jjrel 0..1, k4 0..3), chunk c = jjrel*4 + k4 at lds + c*1024. Chunk =
// exact MFMA B-fragment: lane l <- B[(jj0+jjrel)*16 + (l&15)]
//                                  [k4*32 + (l>>4)*8 .. +8].
__device__ __forceinline__ void stage_half(const ushort_t* __restrict__ pcol,
                                           unsigned char* __restrict__ lds,
                                           int jj0, int l) {
    const ushort_t* g = pcol + (size_t)(jj0 * 16 + (l & 15)) * DDIM + (l >> 4) * 8;
    #pragma unroll
    for (int c = 0; c < 8; ++c) {
        const int jjrel = c >> 2, k4 = c & 3;
        g2lds16(g + jjrel * 16 * DDIM + k4 * 32, lds + c * 1024);
    }
}

// ---- kernel 2: barrier-free wave-private panel pipeline -----------------
// grid (B/128, SPLITS=8), block 256 = 4 waves. Block: 128 rows x 1024 cols
// as 16 panels of 64 cols. Wave w: rows (w>>1)*64..+64, cols (w&1)*32..+32;
// stages its OWN 8 KB half-panel, double-buffered, self-timed vmcnt(8).
__global__ __launch_bounds__(256, 2)
void tile_kernel(const ushort_t* __restrict__ e1b, const ushort_t* __restrict__ e2b,
                 const float* __restrict__ cpos, const float* __restrict__ cneg,
                 float* __restrict__ pmp, float* __restrict__ nmp, int B) {
    __shared__ __align__(16) unsigned char smRaw[4 * WAVE_LDS + CPCN_BYTES];
    float* smCp = (float*)(smRaw + 4 * WAVE_LDS);   // [1024]
    float* smCn = smCp + 1024;                       // [1024]

    const int tid = threadIdx.x;
    const int w   = tid >> 6;
    const int l   = tid & 63;
    const int lq  = l >> 4;          // quad 0..3
    const int lm  = l & 15;
    const int row0 = blockIdx.x * 128;
    const int col0 = blockIdx.y * 1024;
    const int nPanels = 16;

    const int wr  = (w >> 1) * 64;   // wave's row half
    const int wc  = (w & 1) * 32;    // wave's col half within 64-col panel
    const int jj0 = (w & 1) * 2;     // wave's first col-16-block

    unsigned char* myLds = smRaw + w * WAVE_LDS;     // private 2x8 KB

    // prologue: cp,cn FIRST (so vmcnt(8) below retires exactly them),
    // then own half of panel 0.
    g2lds16(cpos + col0 + w * 256 + l * 4, smCp + w * 256);
    g2lds16(cneg + col0 + w * 256 + l * 4, smCn + w * 256);
    stage_half(e2b + (size_t)col0 * DDIM, myLds, jj0, l);
    // outstanding = [cp, cn, stage0 x8] = 10; wait<=8 retires cp,cn only.
    asm volatile("s_waitcnt vmcnt(8)" ::: "memory");
    __syncthreads();                 // ALL waves' cp/cn slabs resident

    // A fragments straight from global: row = row0+wr+i*16+lm,
    // elems [k4*32 + lq*8, +8). L2-resident (e1b = 2 MB, pre-scaled by -2).
    const ushort_t* aG = e1b + (size_t)(row0 + wr + lm) * DDIM + lq * 8;
    short8 afr[4][4];                // [i][k4]: 64 regs, K=128 resident
    #pragma unroll
    for (int i = 0; i < 4; ++i)
        #pragma unroll
        for (int k4 = 0; k4 < 4; ++k4)
            afr[i][k4] = *(const short8*)(aG + i * 16 * DDIM + k4 * 32);

    const unsigned char* bLane = myLds + (size_t)l * 16;

    float pm[4][4], nm[4][4];        // [i][r]: local row = wr + i*16 + lq*4 + r
    #pragma unroll
    for (int i = 0; i < 4; ++i)
        #pragma unroll
        for (int r = 0; r < 4; ++r) { pm[i][r] = -SENT; nm[i][r] = SENT; }

    // main loop: NO barriers. Own-pace ledger per wave:
    //  p=0: outstanding stage0(8)+afr(16)+stage1(8)=32 -> vmcnt(8) retires
    //       stage0+afr, leaves stage1.  p>=1: stage(p)+stage(p+1)=16 ->
    //       vmcnt(8) retires stage(p).  p=15: vmcnt(0).
    for (int p = 0; p < nPanels; ++p) {
        if (p + 1 < nPanels) {
            stage_half(e2b + (size_t)(col0 + (p + 1) * 64) * DDIM,
                       myLds + ((p + 1) & 1) * HALF_BYTES, jj0, l);
            asm volatile("s_waitcnt vmcnt(8)" ::: "memory");
        } else {
            asm volatile("s_waitcnt vmcnt(0)" ::: "memory");
        }

        const unsigned char* bl = bLane + (p & 1) * HALF_BYTES;

        f32x4 accA[4], accB[4];      // jjrel=0 / jjrel=1 accumulators
        #pragma unroll
        for (int i = 0; i < 4; ++i) {
            accA[i] = (f32x4){0.f, 0.f, 0.f, 0.f};
            accB[i] = (f32x4){0.f, 0.f, 0.f, 0.f};
        }

        #pragma unroll
        for (int k4 = 0; k4 < 4; ++k4) {
            const short8 b0 = *(const short8*)(bl + k4 * 1024);          // jjrel 0
            const short8 b1 = *(const short8*)(bl + (4 + k4) * 1024);    // jjrel 1
            #pragma unroll
            for (int i = 0; i < 4; ++i)
                accA[i] = __builtin_amdgcn_mfma_f32_16x16x32_bf16(
                              afr[i][k4], b0, accA[i], 0, 0, 0);
            #pragma unroll
            for (int i = 0; i < 4; ++i)
                accB[i] = __builtin_amdgcn_mfma_f32_16x16x32_bf16(
                              afr[i][k4], b1, accB[i], 0, 0, 0);
        }

        // epilogue: acc = -2*dot; colterm from LDS (lgkm only -> vmem
        // ledger holds exactly the stage DMAs). Paired for v_max3/v_min3.
        {
            const int lcb = p * 64 + wc + lm;            // C/D: col = lane&15
            const float cp0 = smCp[lcb],      cn0 = smCn[lcb];
            const float cp1 = smCp[lcb + 16], cn1 = smCn[lcb + 16];
            #pragma unroll
            for (int i = 0; i < 4; ++i)
                #pragma unroll
                for (int r = 0; r < 4; ++r) {
                    const float d0 = accA[i][r];
                    const float d1 = accB[i][r];
                    pm[i][r] = fmaxf(fmaxf(pm[i][r], d0 + cp0), d1 + cp1);
                    nm[i][r] = fminf(fminf(nm[i][r], d0 + cn0), d1 + cn1);
                }
        }
    }

    // intra-wave: reduce across the 16 column-lanes (rows fixed per (lq,r))
    #pragma unroll
    for (int m = 1; m < 16; m <<= 1) {
        #pragma unroll
        for (int i = 0; i < 4; ++i)
            #pragma unroll
            for (int r = 0; r < 4; ++r) {
                pm[i][r] = fmaxf(pm[i][r], __shfl_xor(pm[i][r], m, 64));
                nm[i][r] = fminf(nm[i][r], __shfl_xor(nm[i][r], m, 64));
            }
    }

    // cross-wave: pairs (0,1),(2,3) share rows over complementary col
    // halves. Overlay scratch on smRaw — explicit barrier first (waves
    // free-ran; wave 0 may still be computing when others arrive).
    float* smP = (float*)smRaw;            // [128]
    float* smN = smP + 128;                // [128]
    __syncthreads();                       // everyone done with private LDS
    if ((w & 1) == 1 && lm == 0) {
        #pragma unroll
        for (int i = 0; i < 4; ++i)
            #pragma unroll
            for (int r = 0; r < 4; ++r) {
                int lr = wr + i * 16 + lq * 4 + r;
                smP[lr] = pm[i][r];
                smN[lr] = nm[i][r];
            }
    }
    __syncthreads();
    if ((w & 1) == 0 && lm == 0) {
        #pragma unroll
        for (int i = 0; i < 4; ++i)
            #pragma unroll
            for (int r = 0; r < 4; ++r) {
                int lr = wr + i * 16 + lq * 4 + r;   // C/D: row = quad*4+reg
                smP[lr] = fmaxf(pm[i][r], smP[lr]);
                smN[lr] = fminf(nm[i][r], smN[lr]);
            }
    }
    __syncthreads();
    if (tid < 128) {                       // coalesced partial store
        pmp[(size_t)blockIdx.y * B + row0 + tid] = smP[tid];
        nmp[(size_t)blockIdx.y * B + row0 + tid] = smN[tid];
    }
}

// ---- kernel 3: per-row combine + hinge; atomic partials; last block divides ----
__global__ void reduce_kernel(const float* __restrict__ pmp, const float* __restrict__ nmp,
                              const float* __restrict__ rowterm, const int* __restrict__ target,
                              float* __restrict__ redsum, int* __restrict__ ticket,
                              float* __restrict__ out, int B) {
    int row = blockIdx.x * blockDim.x + threadIdx.x;    // 32 x 256 = 8192
    float s = 0.f, c = 0.f;
    {
        float pmv = -SENT, nmv = SENT;
        #pragma unroll
        for (int sp = 0; sp < SPLITS; ++sp) {
            pmv = fmaxf(pmv, pmp[(size_t)sp * B + row]);
            nmv = fminf(nmv, nmp[(size_t)sp * B + row]);
        }
        float rt = rowterm[row];
        float dp = sqrtf(fmaxf(rt + pmv, 0.f));
        float dn = sqrtf(fmaxf(rt + nmv, 0.f));
        if (target[row] == 1) {
            s = fmaxf(dp - dn + MARGIN, 0.f);
            c = 1.f;
        }
    }
    #pragma unroll
    for (int off = 32; off > 0; off >>= 1) {
        s += __shfl_down(s, off, 64);
        c += __shfl_down(c, off, 64);
    }
    __shared__ float ls[4], lc[4];
    int wv = threadIdx.x >> 6, ln = threadIdx.x & 63;
    if (ln == 0) { ls[wv] = s; lc[wv] = c; }
    __syncthreads();
    if (threadIdx.x == 0) {
        float ss = ls[0] + ls[1] + ls[2] + ls[3];
        float cc = lc[0] + lc[1] + lc[2] + lc[3];
        atomicAdd(&redsum[0], ss);
        atomicAdd(&redsum[1], cc);
        __threadfence();
        int done = atomicAdd(ticket, 1);
        if (done == (int)gridDim.x - 1) {
            __threadfence();
            float fs = __hip_atomic_load(&redsum[0], __ATOMIC_RELAXED, __HIP_MEMORY_SCOPE_AGENT);
            float fc = __hip_atomic_load(&redsum[1], __ATOMIC_RELAXED, __HIP_MEMORY_SCOPE_AGENT);
            out[0] = fs / fc;
        }
    }
}

extern "C" void kernel_launch(void* const* d_in, const int* in_sizes, int n_in,
                              void* d_out, int out_size, void* d_ws, size_t ws_size,
                              hipStream_t stream) {
    const float* e1     = (const float*)d_in[0];
    const float* e2     = (const float*)d_in[1];
    const int*   target = (const int*)d_in[2];
    float* out = (float*)d_out;
    const int B = in_sizes[2];                       // 8192

    // ws layout: e1b | e2b | rowterm | cpos | cneg | pmp | nmp | redsum | ticket
    char* p = (char*)d_ws;
    ushort_t* e1b  = (ushort_t*)p;   p += (size_t)B * DDIM * 2;   // 2 MB (scaled by -2)
    ushort_t* e2b  = (ushort_t*)p;   p += (size_t)B * DDIM * 2;   // 2 MB
    float* rowterm = (float*)p;      p += (size_t)B * 4;
    float* cpos    = (float*)p;      p += (size_t)B * 4;
    float* cneg    = (float*)p;      p += (size_t)B * 4;
    float* pmp     = (float*)p;      p += (size_t)SPLITS * B * 4; // 256 KB
    float* nmp     = (float*)p;      p += (size_t)SPLITS * B * 4; // 256 KB
    float* redsum  = (float*)p;      p += 2 * 4;
    int*   ticket  = (int*)p;

    {   // prep: 8 lanes/row, 32 rows/block -> 2B/32 = 512 blocks
        int blocks = (2 * B) / 32;
        prep_kernel<<<blocks, 256, 0, stream>>>(e1, e2, target, e1b, e2b,
                                                rowterm, cpos, cneg,
                                                redsum, ticket, B);
    }
    {   // 64 row-blocks x 8 col-splits = 512 blocks; 72 KB LDS, 2 blocks/CU
        dim3 grid(B / 128, SPLITS);
        tile_kernel<<<grid, 256, 0, stream>>>(e1b, e2b, cpos, cneg, pmp, nmp, B);
    }
    reduce_kernel<<<32, 256, 0, stream>>>(pmp, nmp, rowterm, target,
                                          redsum, ticket, out, B);
}